// Round 5
// baseline (143.319 us; speedup 1.0000x reference)
//
#include <hip/hip_runtime.h>
#include <math.h>

#define NB 256
#define ND 2048
#define T_K 10.0f
#define SCAN_BLOCKS 2048

// ---------------------------------------------------------------------------
// Kernel 1: per-row mean & std (ddof=1); fused minbits + done-counter init.
// One block (256 threads) per row; 2 float4 per thread.
// ---------------------------------------------------------------------------
__global__ __launch_bounds__(256) void stats_kernel(const float* __restrict__ feat,
                                                    float* __restrict__ stats,
                                                    unsigned int* __restrict__ minbits,
                                                    unsigned int* __restrict__ donecnt) {
    const int b   = blockIdx.x;
    const int tid = threadIdx.x;
    if (tid == 0) {
        minbits[b] = 0x7F800000u;          // +inf
        if (b == 0) donecnt[0] = 0;        // reset last-block counter each call
    }

    const float4* row = (const float4*)(feat + (size_t)b * ND);
    float sum = 0.f, sumsq = 0.f;
#pragma unroll
    for (int i = 0; i < 2; ++i) {
        float4 v = row[tid + i * 256];
        sum   += v.x + v.y + v.z + v.w;
        sumsq += v.x * v.x + v.y * v.y + v.z * v.z + v.w * v.w;
    }
#pragma unroll
    for (int off = 32; off > 0; off >>= 1) {
        sum   += __shfl_down(sum, off, 64);
        sumsq += __shfl_down(sumsq, off, 64);
    }
    __shared__ float ls[4], lq[4];
    const int lane = tid & 63, wid = tid >> 6;
    if (lane == 0) { ls[wid] = sum; lq[wid] = sumsq; }
    __syncthreads();
    if (tid == 0) {
        float S  = ls[0] + ls[1] + ls[2] + ls[3];
        float Q2 = lq[0] + lq[1] + lq[2] + lq[3];
        float mean = S / (float)ND;
        float var  = (Q2 - S * mean) / (float)(ND - 1);
        var = fmaxf(var, 0.f);
        stats[b]      = mean;
        stats[NB + b] = sqrtf(var);
    }
}

// ---------------------------------------------------------------------------
// Kernel 2: brute-force min scan + fused epilogue.
//   d = (m-mu)^2 + (s-sg)^2 = c_b + [ -2m*mu - 2s*sg + (mu^2+sg^2) ]
// Track min of bracketed d' (2 fma + 1 fmin per pair), add c_b at the end.
// Lane l owns samples b = l+64k (k=0..3); 16 independent fmin chains.
// VMEM broadcast loads (NOT readfirstlane/SMEM — R3 showed the scalar pipe
// serializes under 32 waves/CU). 2-quad unroll keeps VGPR<=64 so
// __launch_bounds__(256,8) holds 8 waves/SIMD for latency hiding.
// Last block to finish computes the output (saves final_kernel launch).
// ---------------------------------------------------------------------------
__global__ __launch_bounds__(256, 8) void scan_kernel(const float* __restrict__ mus,
                                                      const float* __restrict__ sigmas,
                                                      const float* __restrict__ stats,
                                                      unsigned int* __restrict__ minbits,
                                                      unsigned int* __restrict__ donecnt,
                                                      float* __restrict__ out,
                                                      int Q) {
    const int tid  = threadIdx.x;
    const int lane = tid & 63;
    const int wid  = tid >> 6;

    float m2[4], s2[4];
#pragma unroll
    for (int k = 0; k < 4; ++k) {
        m2[k] = -2.f * stats[lane + 64 * k];
        s2[k] = -2.f * stats[NB + lane + 64 * k];
    }

    float acc[4][4];
#pragma unroll
    for (int k = 0; k < 4; ++k)
#pragma unroll
        for (int e = 0; e < 4; ++e) acc[k][e] = INFINITY;

    const int nquad = Q >> 2;
    const int gw    = blockIdx.x * 4 + wid;
    const int nw    = SCAN_BLOCKS * 4;
    const int chunk = (nquad + nw - 1) / nw;
    const int start = gw * chunk;
    const int end   = min(start + chunk, nquad);

    const float4* mu4 = (const float4*)mus;
    const float4* sg4 = (const float4*)sigmas;

#define PROC(MU, SG)                                                                     \
    {                                                                                    \
        const float r0 = fmaf((MU).x, (MU).x, (SG).x * (SG).x);                          \
        const float r1 = fmaf((MU).y, (MU).y, (SG).y * (SG).y);                          \
        const float r2 = fmaf((MU).z, (MU).z, (SG).z * (SG).z);                          \
        const float r3 = fmaf((MU).w, (MU).w, (SG).w * (SG).w);                          \
        _Pragma("unroll")                                                                \
        for (int k = 0; k < 4; ++k) {                                                    \
            acc[k][0] = fminf(acc[k][0], fmaf(m2[k], (MU).x, fmaf(s2[k], (SG).x, r0)));  \
            acc[k][1] = fminf(acc[k][1], fmaf(m2[k], (MU).y, fmaf(s2[k], (SG).y, r1)));  \
            acc[k][2] = fminf(acc[k][2], fmaf(m2[k], (MU).z, fmaf(s2[k], (SG).z, r2)));  \
            acc[k][3] = fminf(acc[k][3], fmaf(m2[k], (MU).w, fmaf(s2[k], (SG).w, r3)));  \
        }                                                                                \
    }

    int iq = start;
    for (; iq + 2 <= end; iq += 2) {
        float4 mu0 = mu4[iq],     sg0 = sg4[iq];
        float4 mu1 = mu4[iq + 1], sg1 = sg4[iq + 1];
        PROC(mu0, sg0);
        PROC(mu1, sg1);
    }
    if (iq < end) {
        float4 mu0 = mu4[iq], sg0 = sg4[iq];
        PROC(mu0, sg0);
    }
    // element tail (Q % 4) — done once by wave 0
    if (gw == 0) {
        for (int q = nquad * 4; q < Q; ++q) {
            float mu = mus[q], sg = sigmas[q];
            float r = fmaf(mu, mu, sg * sg);
#pragma unroll
            for (int k = 0; k < 4; ++k)
                acc[k][0] = fminf(acc[k][0], fmaf(m2[k], mu, fmaf(s2[k], sg, r)));
        }
    }
#undef PROC

    float a[4];
#pragma unroll
    for (int k = 0; k < 4; ++k)
        a[k] = fminf(fminf(acc[k][0], acc[k][1]), fminf(acc[k][2], acc[k][3]));

    __shared__ float red[4][NB];
#pragma unroll
    for (int k = 0; k < 4; ++k) red[wid][lane + 64 * k] = a[k];
    __syncthreads();

    float v = fminf(fminf(red[0][tid], red[1][tid]), fminf(red[2][tid], red[3][tid]));
    // un-shift: d2 = d' + (mean_b^2 + std_b^2); clamp >=0 for bitwise atomicMin
    const float mb = stats[tid], sb = stats[NB + tid];
    v = fmaxf(v + fmaf(mb, mb, sb * sb), 0.f);
    atomicMin(&minbits[tid], __float_as_uint(v));

    // ---- fused epilogue: last block computes T = exp(-T_k * sqrt(min_d2)) ----
    __shared__ int lastFlag;
    __threadfence();                 // publish our atomicMin before counting done
    __syncthreads();
    if (tid == 0) {
        unsigned int old = atomicAdd(donecnt, 1u);
        lastFlag = (old == SCAN_BLOCKS - 1u) ? 1 : 0;
    }
    __syncthreads();
    if (lastFlag) {
        __threadfence();             // acquire: see all blocks' minbits
        unsigned int bits = __hip_atomic_load(&minbits[tid], __ATOMIC_RELAXED,
                                              __HIP_MEMORY_SCOPE_AGENT);
        float d2 = __uint_as_float(bits);
        out[tid] = expf(-T_K * sqrtf(d2));
    }
}

extern "C" void kernel_launch(void* const* d_in, const int* in_sizes, int n_in,
                              void* d_out, int out_size, void* d_ws, size_t ws_size,
                              hipStream_t stream) {
    const float* features = (const float*)d_in[0];
    // d_in[1]=labels, d_in[2]=pred, d_in[3]=confidence -- unused by reference
    const float* queue_mus    = (const float*)d_in[4];
    const float* queue_sigmas = (const float*)d_in[5];
    const int Q = in_sizes[4];

    float*        stats   = (float*)d_ws;                         // 2*NB floats
    unsigned int* minbits = (unsigned int*)((float*)d_ws + 2 * NB); // NB uints
    unsigned int* donecnt = minbits + NB;                          // 1 uint

    stats_kernel<<<NB, 256, 0, stream>>>(features, stats, minbits, donecnt);
    scan_kernel<<<SCAN_BLOCKS, 256, 0, stream>>>(queue_mus, queue_sigmas, stats,
                                                 minbits, donecnt, (float*)d_out, Q);
}

// Round 6
// 58.780 us; speedup vs baseline: 2.4382x; 2.4382x over previous
//
#include <hip/hip_runtime.h>
#include <math.h>

#define NB 256
#define ND 2048
#define T_K 10.0f
#define SCAN_BLOCKS 2048

// ---------------------------------------------------------------------------
// Kernel 1: per-row mean & std (ddof=1); fused minbits init.
// One block (256 threads) per row; 2 float4 per thread.
// ---------------------------------------------------------------------------
__global__ __launch_bounds__(256) void stats_kernel(const float* __restrict__ feat,
                                                    float* __restrict__ stats,
                                                    unsigned int* __restrict__ minbits) {
    const int b   = blockIdx.x;
    const int tid = threadIdx.x;
    if (tid == 0) minbits[b] = 0x7F800000u;  // +inf

    const float4* row = (const float4*)(feat + (size_t)b * ND);
    float sum = 0.f, sumsq = 0.f;
#pragma unroll
    for (int i = 0; i < 2; ++i) {
        float4 v = row[tid + i * 256];
        sum   += v.x + v.y + v.z + v.w;
        sumsq += v.x * v.x + v.y * v.y + v.z * v.z + v.w * v.w;
    }
#pragma unroll
    for (int off = 32; off > 0; off >>= 1) {
        sum   += __shfl_down(sum, off, 64);
        sumsq += __shfl_down(sumsq, off, 64);
    }
    __shared__ float ls[4], lq[4];
    const int lane = tid & 63, wid = tid >> 6;
    if (lane == 0) { ls[wid] = sum; lq[wid] = sumsq; }
    __syncthreads();
    if (tid == 0) {
        float S  = ls[0] + ls[1] + ls[2] + ls[3];
        float Q2 = lq[0] + lq[1] + lq[2] + lq[3];
        float mean = S / (float)ND;
        float var  = (Q2 - S * mean) / (float)(ND - 1);
        var = fmaxf(var, 0.f);
        stats[b]      = mean;
        stats[NB + b] = sqrtf(var);
    }
}

// ---------------------------------------------------------------------------
// Kernel 2: brute-force min scan.
//   d = (m-mu)^2 + (s-sg)^2 = c_b + [ -2m*mu - 2s*sg + (mu^2+sg^2) ]
// Track min of bracketed d' (2 fma + 1 fmin per pair), add c_b at the end.
// Lane l owns samples b = l+64k (k=0..3); 16 independent fmin chains.
// GRID-STRIDE interleave (R2-proven): consecutive waves read consecutive
// quads -> 4 quads/64B line shared across waves -> L1/L2 hits, not cold HBM.
// (R3 showed readfirstlane/SMEM serializes the scalar pipe; R5 showed chunked
// partitioning + threadfence epilogue both regress. Plain VMEM broadcast.)
// ---------------------------------------------------------------------------
__global__ __launch_bounds__(256) void scan_kernel(const float* __restrict__ mus,
                                                   const float* __restrict__ sigmas,
                                                   const float* __restrict__ stats,
                                                   unsigned int* __restrict__ minbits,
                                                   int Q) {
    const int tid  = threadIdx.x;
    const int lane = tid & 63;
    const int wid  = tid >> 6;

    float m2[4], s2[4];
#pragma unroll
    for (int k = 0; k < 4; ++k) {
        m2[k] = -2.f * stats[lane + 64 * k];
        s2[k] = -2.f * stats[NB + lane + 64 * k];
    }

    float acc[4][4];
#pragma unroll
    for (int k = 0; k < 4; ++k)
#pragma unroll
        for (int e = 0; e < 4; ++e) acc[k][e] = INFINITY;

    const int nquad = Q >> 2;
    const int gw    = blockIdx.x * 4 + wid;
    const int nw    = SCAN_BLOCKS * 4;
    const float4* mu4 = (const float4*)mus;
    const float4* sg4 = (const float4*)sigmas;

    for (int iq = gw; iq < nquad; iq += nw) {
        float4 mu = mu4[iq];
        float4 sg = sg4[iq];
        const float r0 = fmaf(mu.x, mu.x, sg.x * sg.x);
        const float r1 = fmaf(mu.y, mu.y, sg.y * sg.y);
        const float r2 = fmaf(mu.z, mu.z, sg.z * sg.z);
        const float r3 = fmaf(mu.w, mu.w, sg.w * sg.w);
#pragma unroll
        for (int k = 0; k < 4; ++k) {
            acc[k][0] = fminf(acc[k][0], fmaf(m2[k], mu.x, fmaf(s2[k], sg.x, r0)));
            acc[k][1] = fminf(acc[k][1], fmaf(m2[k], mu.y, fmaf(s2[k], sg.y, r1)));
            acc[k][2] = fminf(acc[k][2], fmaf(m2[k], mu.z, fmaf(s2[k], sg.z, r2)));
            acc[k][3] = fminf(acc[k][3], fmaf(m2[k], mu.w, fmaf(s2[k], sg.w, r3)));
        }
    }
    // element tail (Q % 4) — done once by wave 0 (Q=880880 -> empty, kept for safety)
    if (gw == 0) {
        for (int q = nquad * 4; q < Q; ++q) {
            float mu = mus[q], sg = sigmas[q];
            float r = fmaf(mu, mu, sg * sg);
#pragma unroll
            for (int k = 0; k < 4; ++k)
                acc[k][0] = fminf(acc[k][0], fmaf(m2[k], mu, fmaf(s2[k], sg, r)));
        }
    }

    float a[4];
#pragma unroll
    for (int k = 0; k < 4; ++k)
        a[k] = fminf(fminf(acc[k][0], acc[k][1]), fminf(acc[k][2], acc[k][3]));

    __shared__ float red[4][NB];
#pragma unroll
    for (int k = 0; k < 4; ++k) red[wid][lane + 64 * k] = a[k];
    __syncthreads();

    float v = fminf(fminf(red[0][tid], red[1][tid]), fminf(red[2][tid], red[3][tid]));
    // un-shift: d2 = d' + (mean_b^2 + std_b^2); clamp >=0 for bitwise atomicMin
    const float mb = stats[tid], sb = stats[NB + tid];
    v = fmaxf(v + fmaf(mb, mb, sb * sb), 0.f);
    atomicMin(&minbits[tid], __float_as_uint(v));
}

// ---------------------------------------------------------------------------
// Kernel 3: T = exp(-T_k * sqrt(min_sq))
// ---------------------------------------------------------------------------
__global__ void final_kernel(const unsigned int* __restrict__ minbits,
                             float* __restrict__ out) {
    const int b = threadIdx.x;
    float d2 = __uint_as_float(minbits[b]);
    out[b] = expf(-T_K * sqrtf(d2));
}

extern "C" void kernel_launch(void* const* d_in, const int* in_sizes, int n_in,
                              void* d_out, int out_size, void* d_ws, size_t ws_size,
                              hipStream_t stream) {
    const float* features = (const float*)d_in[0];
    // d_in[1]=labels, d_in[2]=pred, d_in[3]=confidence -- unused by reference
    const float* queue_mus    = (const float*)d_in[4];
    const float* queue_sigmas = (const float*)d_in[5];
    const int Q = in_sizes[4];

    float*        stats   = (float*)d_ws;                           // 2*NB floats
    unsigned int* minbits = (unsigned int*)((float*)d_ws + 2 * NB); // NB uints

    stats_kernel<<<NB, 256, 0, stream>>>(features, stats, minbits);
    scan_kernel<<<SCAN_BLOCKS, 256, 0, stream>>>(queue_mus, queue_sigmas, stats,
                                                 minbits, Q);
    final_kernel<<<1, NB, 0, stream>>>(minbits, (float*)d_out);
}

// Round 7
// 56.397 us; speedup vs baseline: 2.5413x; 1.0423x over previous
//
#include <hip/hip_runtime.h>
#include <math.h>

#define NB 256
#define ND 2048
#define T_K 10.0f
#define SCAN_BLOCKS 2048

// ---------------------------------------------------------------------------
// Kernel 1: per-row mean & std (ddof=1); fused minbits init.
// One block (256 threads) per row; 2 float4 per thread.
// ---------------------------------------------------------------------------
__global__ __launch_bounds__(256) void stats_kernel(const float* __restrict__ feat,
                                                    float* __restrict__ stats,
                                                    unsigned int* __restrict__ minbits) {
    const int b   = blockIdx.x;
    const int tid = threadIdx.x;
    if (tid == 0) minbits[b] = 0x7F800000u;  // +inf

    const float4* row = (const float4*)(feat + (size_t)b * ND);
    float sum = 0.f, sumsq = 0.f;
#pragma unroll
    for (int i = 0; i < 2; ++i) {
        float4 v = row[tid + i * 256];
        sum   += v.x + v.y + v.z + v.w;
        sumsq += v.x * v.x + v.y * v.y + v.z * v.z + v.w * v.w;
    }
#pragma unroll
    for (int off = 32; off > 0; off >>= 1) {
        sum   += __shfl_down(sum, off, 64);
        sumsq += __shfl_down(sumsq, off, 64);
    }
    __shared__ float ls[4], lq[4];
    const int lane = tid & 63, wid = tid >> 6;
    if (lane == 0) { ls[wid] = sum; lq[wid] = sumsq; }
    __syncthreads();
    if (tid == 0) {
        float S  = ls[0] + ls[1] + ls[2] + ls[3];
        float Q2 = lq[0] + lq[1] + lq[2] + lq[3];
        float mean = S / (float)ND;
        float var  = (Q2 - S * mean) / (float)(ND - 1);
        var = fmaxf(var, 0.f);
        stats[b]      = mean;
        stats[NB + b] = sqrtf(var);
    }
}

// ---------------------------------------------------------------------------
// Kernel 2: brute-force min scan, 4-quad batched rounds.
//   d = (m-mu)^2 + (s-sg)^2 = c_b + [ -2m*mu - 2s*sg + (mu^2+sg^2) ]
// Track min of bracketed d' (2 fma + 1 fmin per pair), add c_b at the end.
// Lane l owns samples b = l+64k (k=0..3); 16 independent fmin chains.
// R6 post-mortem: 1 quad/round = MLP 2 -> round-trip latency bound (~4900
// cyc/round measured). This version: each wave loads ONE 64B LINE per array
// per round (4 quads, 8 dwordx4 in flight), grid-striding by 4-quad groups.
// Compiler's counted vmcnt waits overlap per-quad compute with loads.
// ---------------------------------------------------------------------------
__global__ __launch_bounds__(256) void scan_kernel(const float* __restrict__ mus,
                                                   const float* __restrict__ sigmas,
                                                   const float* __restrict__ stats,
                                                   unsigned int* __restrict__ minbits,
                                                   int Q) {
    const int tid  = threadIdx.x;
    const int lane = tid & 63;
    const int wid  = tid >> 6;

    float m2[4], s2[4];
#pragma unroll
    for (int k = 0; k < 4; ++k) {
        m2[k] = -2.f * stats[lane + 64 * k];
        s2[k] = -2.f * stats[NB + lane + 64 * k];
    }

    float acc[4][4];
#pragma unroll
    for (int k = 0; k < 4; ++k)
#pragma unroll
        for (int e = 0; e < 4; ++e) acc[k][e] = INFINITY;

    const int nquad  = Q >> 2;          // 220220
    const int ngroup = nquad >> 2;      // 55055 groups of 4 quads (one 64B line)
    const int gw     = blockIdx.x * 4 + wid;
    const int nw     = SCAN_BLOCKS * 4;
    const float4* mu4 = (const float4*)mus;
    const float4* sg4 = (const float4*)sigmas;

#define PROC(MU, SG)                                                                     \
    {                                                                                    \
        const float r0 = fmaf((MU).x, (MU).x, (SG).x * (SG).x);                          \
        const float r1 = fmaf((MU).y, (MU).y, (SG).y * (SG).y);                          \
        const float r2 = fmaf((MU).z, (MU).z, (SG).z * (SG).z);                          \
        const float r3 = fmaf((MU).w, (MU).w, (SG).w * (SG).w);                          \
        _Pragma("unroll")                                                                \
        for (int k = 0; k < 4; ++k) {                                                    \
            acc[k][0] = fminf(acc[k][0], fmaf(m2[k], (MU).x, fmaf(s2[k], (SG).x, r0)));  \
            acc[k][1] = fminf(acc[k][1], fmaf(m2[k], (MU).y, fmaf(s2[k], (SG).y, r1)));  \
            acc[k][2] = fminf(acc[k][2], fmaf(m2[k], (MU).z, fmaf(s2[k], (SG).z, r2)));  \
            acc[k][3] = fminf(acc[k][3], fmaf(m2[k], (MU).w, fmaf(s2[k], (SG).w, r3)));  \
        }                                                                                \
    }

    for (int g = gw; g < ngroup; g += nw) {
        const int base = g * 4;
        // 8 loads issued back-to-back: one 64B line from each array.
        float4 mu0 = mu4[base + 0], mu1 = mu4[base + 1];
        float4 mu2 = mu4[base + 2], mu3 = mu4[base + 3];
        float4 sg0 = sg4[base + 0], sg1 = sg4[base + 1];
        float4 sg2 = sg4[base + 2], sg3 = sg4[base + 3];
        PROC(mu0, sg0);
        PROC(mu1, sg1);
        PROC(mu2, sg2);
        PROC(mu3, sg3);
    }

    // leftover quads (nquad % 4) + element tail (Q % 4) — wave 0 only.
    // (Q=880880: both empty; kept for generality.)
    if (gw == 0) {
        for (int iq = ngroup * 4; iq < nquad; ++iq) {
            float4 mu = mu4[iq], sg = sg4[iq];
            PROC(mu, sg);
        }
        for (int q = nquad * 4; q < Q; ++q) {
            float mu = mus[q], sg = sigmas[q];
            float r = fmaf(mu, mu, sg * sg);
#pragma unroll
            for (int k = 0; k < 4; ++k)
                acc[k][0] = fminf(acc[k][0], fmaf(m2[k], mu, fmaf(s2[k], sg, r)));
        }
    }
#undef PROC

    float a[4];
#pragma unroll
    for (int k = 0; k < 4; ++k)
        a[k] = fminf(fminf(acc[k][0], acc[k][1]), fminf(acc[k][2], acc[k][3]));

    __shared__ float red[4][NB];
#pragma unroll
    for (int k = 0; k < 4; ++k) red[wid][lane + 64 * k] = a[k];
    __syncthreads();

    float v = fminf(fminf(red[0][tid], red[1][tid]), fminf(red[2][tid], red[3][tid]));
    // un-shift: d2 = d' + (mean_b^2 + std_b^2); clamp >=0 for bitwise atomicMin
    const float mb = stats[tid], sb = stats[NB + tid];
    v = fmaxf(v + fmaf(mb, mb, sb * sb), 0.f);
    atomicMin(&minbits[tid], __float_as_uint(v));
}

// ---------------------------------------------------------------------------
// Kernel 3: T = exp(-T_k * sqrt(min_sq))
// ---------------------------------------------------------------------------
__global__ void final_kernel(const unsigned int* __restrict__ minbits,
                             float* __restrict__ out) {
    const int b = threadIdx.x;
    float d2 = __uint_as_float(minbits[b]);
    out[b] = expf(-T_K * sqrtf(d2));
}

extern "C" void kernel_launch(void* const* d_in, const int* in_sizes, int n_in,
                              void* d_out, int out_size, void* d_ws, size_t ws_size,
                              hipStream_t stream) {
    const float* features = (const float*)d_in[0];
    // d_in[1]=labels, d_in[2]=pred, d_in[3]=confidence -- unused by reference
    const float* queue_mus    = (const float*)d_in[4];
    const float* queue_sigmas = (const float*)d_in[5];
    const int Q = in_sizes[4];

    float*        stats   = (float*)d_ws;                           // 2*NB floats
    unsigned int* minbits = (unsigned int*)((float*)d_ws + 2 * NB); // NB uints

    stats_kernel<<<NB, 256, 0, stream>>>(features, stats, minbits);
    scan_kernel<<<SCAN_BLOCKS, 256, 0, stream>>>(queue_mus, queue_sigmas, stats,
                                                 minbits, Q);
    final_kernel<<<1, NB, 0, stream>>>(minbits, (float*)d_out);
}

// Round 10
// 50.127 us; speedup vs baseline: 2.8591x; 1.1251x over previous
//
#include <hip/hip_runtime.h>
#include <math.h>

#define NB 256
#define ND 2048
#define T_K 10.0f
#define CHUNK_QUADS 128   // 512 queue points per block; 2x float4[128] = 4 KB LDS stage

// ---------------------------------------------------------------------------
// Kernel 1: per-row mean & std (ddof=1); fused minbits init.
// One block (256 threads) per row; 2 float4 per thread.
// ---------------------------------------------------------------------------
__global__ __launch_bounds__(256) void stats_kernel(const float* __restrict__ feat,
                                                    float* __restrict__ stats,
                                                    unsigned int* __restrict__ minbits) {
    const int b   = blockIdx.x;
    const int tid = threadIdx.x;
    if (tid == 0) minbits[b] = 0x7F800000u;  // +inf

    const float4* row = (const float4*)(feat + (size_t)b * ND);
    float sum = 0.f, sumsq = 0.f;
#pragma unroll
    for (int i = 0; i < 2; ++i) {
        float4 v = row[tid + i * 256];
        sum   += v.x + v.y + v.z + v.w;
        sumsq += v.x * v.x + v.y * v.y + v.z * v.z + v.w * v.w;
    }
#pragma unroll
    for (int off = 32; off > 0; off >>= 1) {
        sum   += __shfl_down(sum, off, 64);
        sumsq += __shfl_down(sumsq, off, 64);
    }
    __shared__ float ls[4], lq[4];
    const int lane = tid & 63, wid = tid >> 6;
    if (lane == 0) { ls[wid] = sum; lq[wid] = sumsq; }
    __syncthreads();
    if (tid == 0) {
        float S  = ls[0] + ls[1] + ls[2] + ls[3];
        float Q2 = lq[0] + lq[1] + lq[2] + lq[3];
        float mean = S / (float)ND;
        float var  = (Q2 - S * mean) / (float)(ND - 1);
        var = fmaxf(var, 0.f);
        stats[b]      = mean;
        stats[NB + b] = sqrtf(var);
    }
}

// ---------------------------------------------------------------------------
// Kernel 2: brute-force min scan, LDS-staged per-block queue slice.
//   d = (m-mu)^2 + (s-sg)^2 = c_b + [ -2m*mu - 2s*sg + (mu^2+sg^2) ]
// R7 post-mortem: grid-stride makes every block walk all 7 MB -> per-XCD L2
// (4 MB) thrashes -> ~4000 cyc effective load latency that no per-wave MLP
// hides. Here each block owns a 512-point slice: staging issues ALL slice
// lines at once (one round trip, coalesced, each line read exactly once
// device-wide), then waves consume via wave-uniform ds_read_b128 broadcasts.
// Lane l owns samples b = l+64k (k=0..3); 16 independent fmin chains.
// ---------------------------------------------------------------------------
__global__ __launch_bounds__(256) void scan_kernel(const float* __restrict__ mus,
                                                   const float* __restrict__ sigmas,
                                                   const float* __restrict__ stats,
                                                   unsigned int* __restrict__ minbits,
                                                   int Q) {
    const int tid  = threadIdx.x;
    const int lane = tid & 63;
    const int wid  = tid >> 6;

    __shared__ float4 lmu[CHUNK_QUADS];
    __shared__ float4 lsg[CHUNK_QUADS];

    const int nquad = Q >> 2;
    const int base  = blockIdx.x * CHUNK_QUADS;
    const int bqn   = min(CHUNK_QUADS, nquad - base);   // slice length in quads (>0 by grid sizing)

    // ---- stage: threads 0..127 load mu quads, 128..255 load sg quads ----
    {
        const float4* mu4 = (const float4*)mus;
        const float4* sg4 = (const float4*)sigmas;
        if (tid < 128) {
            if (tid < bqn) lmu[tid] = mu4[base + tid];
        } else {
            const int t = tid - 128;
            if (t < bqn) lsg[t] = sg4[base + t];
        }
    }

    // per-lane sample constants (overlaps with staging latency)
    float m2[4], s2[4];
#pragma unroll
    for (int k = 0; k < 4; ++k) {
        m2[k] = -2.f * stats[lane + 64 * k];
        s2[k] = -2.f * stats[NB + lane + 64 * k];
    }

    float acc[4][4];
#pragma unroll
    for (int k = 0; k < 4; ++k)
#pragma unroll
        for (int e = 0; e < 4; ++e) acc[k][e] = INFINITY;

    __syncthreads();

    // ---- inner loop: wave-uniform LDS broadcast reads, 4 waves split slice ----
#pragma unroll 4
    for (int iq = wid; iq < bqn; iq += 4) {
        float4 mu = lmu[iq];
        float4 sg = lsg[iq];
        const float r0 = fmaf(mu.x, mu.x, sg.x * sg.x);
        const float r1 = fmaf(mu.y, mu.y, sg.y * sg.y);
        const float r2 = fmaf(mu.z, mu.z, sg.z * sg.z);
        const float r3 = fmaf(mu.w, mu.w, sg.w * sg.w);
#pragma unroll
        for (int k = 0; k < 4; ++k) {
            acc[k][0] = fminf(acc[k][0], fmaf(m2[k], mu.x, fmaf(s2[k], sg.x, r0)));
            acc[k][1] = fminf(acc[k][1], fmaf(m2[k], mu.y, fmaf(s2[k], sg.y, r1)));
            acc[k][2] = fminf(acc[k][2], fmaf(m2[k], mu.z, fmaf(s2[k], sg.z, r2)));
            acc[k][3] = fminf(acc[k][3], fmaf(m2[k], mu.w, fmaf(s2[k], sg.w, r3)));
        }
    }

    // element tail (Q % 4) — block 0 / wave 0, straight from global.
    // (Q=880880 is divisible by 4 -> empty; kept for generality.)
    if (blockIdx.x == 0 && wid == 0) {
        for (int q = nquad * 4; q < Q; ++q) {
            float mu = mus[q], sg = sigmas[q];
            float r = fmaf(mu, mu, sg * sg);
#pragma unroll
            for (int k = 0; k < 4; ++k)
                acc[k][0] = fminf(acc[k][0], fmaf(m2[k], mu, fmaf(s2[k], sg, r)));
        }
    }

    float a[4];
#pragma unroll
    for (int k = 0; k < 4; ++k)
        a[k] = fminf(fminf(acc[k][0], acc[k][1]), fminf(acc[k][2], acc[k][3]));

    __shared__ float red[4][NB];
#pragma unroll
    for (int k = 0; k < 4; ++k) red[wid][lane + 64 * k] = a[k];
    __syncthreads();

    float v = fminf(fminf(red[0][tid], red[1][tid]), fminf(red[2][tid], red[3][tid]));
    // un-shift: d2 = d' + (mean_b^2 + std_b^2); clamp >=0 for bitwise atomicMin
    const float mb = stats[tid], sb = stats[NB + tid];
    v = fmaxf(v + fmaf(mb, mb, sb * sb), 0.f);
    atomicMin(&minbits[tid], __float_as_uint(v));
}

// ---------------------------------------------------------------------------
// Kernel 3: T = exp(-T_k * sqrt(min_sq))
// ---------------------------------------------------------------------------
__global__ void final_kernel(const unsigned int* __restrict__ minbits,
                             float* __restrict__ out) {
    const int b = threadIdx.x;
    float d2 = __uint_as_float(minbits[b]);
    out[b] = expf(-T_K * sqrtf(d2));
}

extern "C" void kernel_launch(void* const* d_in, const int* in_sizes, int n_in,
                              void* d_out, int out_size, void* d_ws, size_t ws_size,
                              hipStream_t stream) {
    const float* features = (const float*)d_in[0];
    // d_in[1]=labels, d_in[2]=pred, d_in[3]=confidence -- unused by reference
    const float* queue_mus    = (const float*)d_in[4];
    const float* queue_sigmas = (const float*)d_in[5];
    const int Q = in_sizes[4];

    float*        stats   = (float*)d_ws;                           // 2*NB floats
    unsigned int* minbits = (unsigned int*)((float*)d_ws + 2 * NB); // NB uints

    const int nquad   = Q >> 2;
    const int nblocks = (nquad + CHUNK_QUADS - 1) / CHUNK_QUADS;    // 1721 for Q=880880

    stats_kernel<<<NB, 256, 0, stream>>>(features, stats, minbits);
    scan_kernel<<<nblocks, 256, 0, stream>>>(queue_mus, queue_sigmas, stats,
                                             minbits, Q);
    final_kernel<<<1, NB, 0, stream>>>(minbits, (float*)d_out);
}

// Round 11
// 29.794 us; speedup vs baseline: 4.8104x; 1.6825x over previous
//
#include <hip/hip_runtime.h>
#include <math.h>

#define NB 256
#define ND 2048
#define T_K 10.0f
#define CHUNK_QUADS 256   // 1024 queue points per block; 2x float4[256] = 8 KB LDS stage

// ---------------------------------------------------------------------------
// Kernel 1: per-row mean & std (ddof=1); fused minbits init (fallback path).
// ---------------------------------------------------------------------------
__global__ __launch_bounds__(256) void stats_kernel(const float* __restrict__ feat,
                                                    float* __restrict__ stats,
                                                    unsigned int* __restrict__ minbits) {
    const int b   = blockIdx.x;
    const int tid = threadIdx.x;
    if (tid == 0) minbits[b] = 0x7F800000u;  // +inf

    const float4* row = (const float4*)(feat + (size_t)b * ND);
    float sum = 0.f, sumsq = 0.f;
#pragma unroll
    for (int i = 0; i < 2; ++i) {
        float4 v = row[tid + i * 256];
        sum   += v.x + v.y + v.z + v.w;
        sumsq += v.x * v.x + v.y * v.y + v.z * v.z + v.w * v.w;
    }
#pragma unroll
    for (int off = 32; off > 0; off >>= 1) {
        sum   += __shfl_down(sum, off, 64);
        sumsq += __shfl_down(sumsq, off, 64);
    }
    __shared__ float ls[4], lq[4];
    const int lane = tid & 63, wid = tid >> 6;
    if (lane == 0) { ls[wid] = sum; lq[wid] = sumsq; }
    __syncthreads();
    if (tid == 0) {
        float S  = ls[0] + ls[1] + ls[2] + ls[3];
        float Q2 = lq[0] + lq[1] + lq[2] + lq[3];
        float mean = S / (float)ND;
        float var  = (Q2 - S * mean) / (float)(ND - 1);
        var = fmaxf(var, 0.f);
        stats[b]      = mean;
        stats[NB + b] = sqrtf(var);
    }
}

// ---------------------------------------------------------------------------
// Scan body (shared by both epilogues): LDS-staged slice, 16 fmin chains.
//   d = (m-mu)^2 + (s-sg)^2 = c_b + [ -2m*mu - 2s*sg + (mu^2+sg^2) ]
// R2..R10 post-mortem: scan time tracked BLOCK COUNT, not math/MLP — the
// per-block 256-wide atomicMin into one 1KB array (16 lines) serializes at
// the coherence point (~440K RMW / 16 lines * ~4cyc ~= 46us = every measured
// time). Epilogue here: per-block PRIVATE partial writes, zero contention;
// a separate 256-block reduce kernel folds partials + final transform.
// ---------------------------------------------------------------------------
template <bool ATOMIC_PATH>
__global__ __launch_bounds__(256) void scan_kernel_t(const float* __restrict__ mus,
                                                     const float* __restrict__ sigmas,
                                                     const float* __restrict__ stats,
                                                     float* __restrict__ partial,       // [nblocks*NB] (partial path)
                                                     unsigned int* __restrict__ minbits,// (atomic fallback)
                                                     int Q) {
    const int tid  = threadIdx.x;
    const int lane = tid & 63;
    const int wid  = tid >> 6;

    __shared__ float4 lmu[CHUNK_QUADS];
    __shared__ float4 lsg[CHUNK_QUADS];

    const int nquad = Q >> 2;
    const int base  = blockIdx.x * CHUNK_QUADS;
    const int bqn   = min(CHUNK_QUADS, nquad - base);

    // ---- stage: every thread loads one mu quad and one sg quad ----
    {
        const float4* mu4 = (const float4*)mus;
        const float4* sg4 = (const float4*)sigmas;
        if (tid < bqn) {
            lmu[tid] = mu4[base + tid];
            lsg[tid] = sg4[base + tid];
        }
    }

    float m2[4], s2[4];
#pragma unroll
    for (int k = 0; k < 4; ++k) {
        m2[k] = -2.f * stats[lane + 64 * k];
        s2[k] = -2.f * stats[NB + lane + 64 * k];
    }

    float acc[4][4];
#pragma unroll
    for (int k = 0; k < 4; ++k)
#pragma unroll
        for (int e = 0; e < 4; ++e) acc[k][e] = INFINITY;

    __syncthreads();

    // ---- inner loop: wave-uniform LDS broadcast reads, 4 waves split slice ----
#pragma unroll 4
    for (int iq = wid; iq < bqn; iq += 4) {
        float4 mu = lmu[iq];
        float4 sg = lsg[iq];
        const float r0 = fmaf(mu.x, mu.x, sg.x * sg.x);
        const float r1 = fmaf(mu.y, mu.y, sg.y * sg.y);
        const float r2 = fmaf(mu.z, mu.z, sg.z * sg.z);
        const float r3 = fmaf(mu.w, mu.w, sg.w * sg.w);
#pragma unroll
        for (int k = 0; k < 4; ++k) {
            acc[k][0] = fminf(acc[k][0], fmaf(m2[k], mu.x, fmaf(s2[k], sg.x, r0)));
            acc[k][1] = fminf(acc[k][1], fmaf(m2[k], mu.y, fmaf(s2[k], sg.y, r1)));
            acc[k][2] = fminf(acc[k][2], fmaf(m2[k], mu.z, fmaf(s2[k], sg.z, r2)));
            acc[k][3] = fminf(acc[k][3], fmaf(m2[k], mu.w, fmaf(s2[k], sg.w, r3)));
        }
    }

    // element tail (Q % 4) — block 0 / wave 0, straight from global (empty for Q=880880)
    if (blockIdx.x == 0 && wid == 0) {
        for (int q = nquad * 4; q < Q; ++q) {
            float mu = mus[q], sg = sigmas[q];
            float r = fmaf(mu, mu, sg * sg);
#pragma unroll
            for (int k = 0; k < 4; ++k)
                acc[k][0] = fminf(acc[k][0], fmaf(m2[k], mu, fmaf(s2[k], sg, r)));
        }
    }

    float a[4];
#pragma unroll
    for (int k = 0; k < 4; ++k)
        a[k] = fminf(fminf(acc[k][0], acc[k][1]), fminf(acc[k][2], acc[k][3]));

    __shared__ float red[4][NB];
#pragma unroll
    for (int k = 0; k < 4; ++k) red[wid][lane + 64 * k] = a[k];
    __syncthreads();

    float v = fminf(fminf(red[0][tid], red[1][tid]), fminf(red[2][tid], red[3][tid]));
    // un-shift: d2 = d' + (mean_b^2 + std_b^2); clamp >=0
    const float mb = stats[tid], sb = stats[NB + tid];
    v = fmaxf(v + fmaf(mb, mb, sb * sb), 0.f);

    if (ATOMIC_PATH) {
        atomicMin(&minbits[tid], __float_as_uint(v));   // nonneg: uint order == float order
    } else {
        partial[(size_t)blockIdx.x * NB + tid] = v;     // private slot, coalesced, no contention
    }
}

// ---------------------------------------------------------------------------
// Kernel 3a (partial path): one block per sample b; min over nblocks partials,
// fused final transform T = exp(-T_k * sqrt(min_d2)).
// Reads partial[i*NB + b]: stride-1KB per thread but L2-resident (<1MB).
// ---------------------------------------------------------------------------
__global__ __launch_bounds__(256) void reduce_kernel(const float* __restrict__ partial,
                                                     float* __restrict__ out,
                                                     int nblocks) {
    const int b   = blockIdx.x;
    const int tid = threadIdx.x;
    float v = INFINITY;
    for (int i = tid; i < nblocks; i += 256)
        v = fminf(v, partial[(size_t)i * NB + b]);
#pragma unroll
    for (int off = 32; off > 0; off >>= 1)
        v = fminf(v, __shfl_down(v, off, 64));
    __shared__ float w[4];
    const int lane = tid & 63, wid = tid >> 6;
    if (lane == 0) w[wid] = v;
    __syncthreads();
    if (tid == 0) {
        float m = fminf(fminf(w[0], w[1]), fminf(w[2], w[3]));
        out[b] = expf(-T_K * sqrtf(m));
    }
}

// ---------------------------------------------------------------------------
// Kernel 3b (atomic fallback): T = exp(-T_k * sqrt(min_sq))
// ---------------------------------------------------------------------------
__global__ void final_kernel(const unsigned int* __restrict__ minbits,
                             float* __restrict__ out) {
    const int b = threadIdx.x;
    float d2 = __uint_as_float(minbits[b]);
    out[b] = expf(-T_K * sqrtf(d2));
}

extern "C" void kernel_launch(void* const* d_in, const int* in_sizes, int n_in,
                              void* d_out, int out_size, void* d_ws, size_t ws_size,
                              hipStream_t stream) {
    const float* features = (const float*)d_in[0];
    // d_in[1]=labels, d_in[2]=pred, d_in[3]=confidence -- unused by reference
    const float* queue_mus    = (const float*)d_in[4];
    const float* queue_sigmas = (const float*)d_in[5];
    const int Q = in_sizes[4];

    const int nquad   = Q >> 2;
    const int nblocks = (nquad + CHUNK_QUADS - 1) / CHUNK_QUADS;   // 861 for Q=880880

    float*        stats   = (float*)d_ws;                            // 2*NB floats
    unsigned int* minbits = (unsigned int*)((float*)d_ws + 2 * NB);  // NB uints
    float*        partial = (float*)(minbits + NB);                  // nblocks*NB floats

    const size_t need = (size_t)(2 * NB) * 4 + (size_t)NB * 4 + (size_t)nblocks * NB * 4;

    stats_kernel<<<NB, 256, 0, stream>>>(features, stats, minbits);
    if (ws_size >= need) {
        scan_kernel_t<false><<<nblocks, 256, 0, stream>>>(queue_mus, queue_sigmas, stats,
                                                          partial, minbits, Q);
        reduce_kernel<<<NB, 256, 0, stream>>>(partial, (float*)d_out, nblocks);
    } else {
        scan_kernel_t<true><<<nblocks, 256, 0, stream>>>(queue_mus, queue_sigmas, stats,
                                                         partial, minbits, Q);
        final_kernel<<<1, NB, 0, stream>>>(minbits, (float*)d_out);
    }
}

// Round 12
// 29.524 us; speedup vs baseline: 4.8543x; 1.0091x over previous
//
#include <hip/hip_runtime.h>
#include <math.h>

#define NB 256
#define ND 2048
#define T_K 10.0f
#define CHUNK_QUADS 128   // 512 queue points per block -> 1721 blocks (6.7/CU, 1.04 imbalance)

// ---------------------------------------------------------------------------
// Kernel 1: per-row mean & std (ddof=1); fused minbits init (fallback path).
// ---------------------------------------------------------------------------
__global__ __launch_bounds__(256) void stats_kernel(const float* __restrict__ feat,
                                                    float* __restrict__ stats,
                                                    unsigned int* __restrict__ minbits) {
    const int b   = blockIdx.x;
    const int tid = threadIdx.x;
    if (tid == 0) minbits[b] = 0x7F800000u;  // +inf

    const float4* row = (const float4*)(feat + (size_t)b * ND);
    float sum = 0.f, sumsq = 0.f;
#pragma unroll
    for (int i = 0; i < 2; ++i) {
        float4 v = row[tid + i * 256];
        sum   += v.x + v.y + v.z + v.w;
        sumsq += v.x * v.x + v.y * v.y + v.z * v.z + v.w * v.w;
    }
#pragma unroll
    for (int off = 32; off > 0; off >>= 1) {
        sum   += __shfl_down(sum, off, 64);
        sumsq += __shfl_down(sumsq, off, 64);
    }
    __shared__ float ls[4], lq[4];
    const int lane = tid & 63, wid = tid >> 6;
    if (lane == 0) { ls[wid] = sum; lq[wid] = sumsq; }
    __syncthreads();
    if (tid == 0) {
        float S  = ls[0] + ls[1] + ls[2] + ls[3];
        float Q2 = lq[0] + lq[1] + lq[2] + lq[3];
        float mean = S / (float)ND;
        float var  = (Q2 - S * mean) / (float)(ND - 1);
        var = fmaxf(var, 0.f);
        stats[b]      = mean;
        stats[NB + b] = sqrtf(var);
    }
}

// ---------------------------------------------------------------------------
// Scan: LDS-staged slice, 16 fmin chains, r precomputed at stage time.
//   d = (m-mu)^2 + (s-sg)^2 = c_b + [ -2m*mu - 2s*sg + (mu^2+sg^2) ]
//                                                      ^^^^^^^^^^^ = r, per
// queue point -- computed ONCE per quad during staging (was 8 VALU/quad/wave
// in the inner loop). R11 confirmed the atomic-free epilogue (50->29.8us);
// this round: 1721 blocks for CU balance + r-precompute for -14% inner VALU.
// ---------------------------------------------------------------------------
template <bool ATOMIC_PATH>
__global__ __launch_bounds__(256) void scan_kernel_t(const float* __restrict__ mus,
                                                     const float* __restrict__ sigmas,
                                                     const float* __restrict__ stats,
                                                     float* __restrict__ partial,       // [nblocks*NB]
                                                     unsigned int* __restrict__ minbits,// fallback
                                                     int Q) {
    const int tid  = threadIdx.x;
    const int lane = tid & 63;
    const int wid  = tid >> 6;

    __shared__ float4 lmu[CHUNK_QUADS];
    __shared__ float4 lsg[CHUNK_QUADS];
    __shared__ float4 lr [CHUNK_QUADS];

    const int nquad = Q >> 2;
    const int base  = blockIdx.x * CHUNK_QUADS;
    const int bqn   = min(CHUNK_QUADS, nquad - base);

    // ---- stage: threads 0..127 each own one quad: load mu+sg, derive r ----
    if (tid < 128 && tid < bqn) {
        const float4* mu4 = (const float4*)mus;
        const float4* sg4 = (const float4*)sigmas;
        float4 mu = mu4[base + tid];
        float4 sg = sg4[base + tid];
        lmu[tid] = mu;
        lsg[tid] = sg;
        float4 r;
        r.x = fmaf(mu.x, mu.x, sg.x * sg.x);
        r.y = fmaf(mu.y, mu.y, sg.y * sg.y);
        r.z = fmaf(mu.z, mu.z, sg.z * sg.z);
        r.w = fmaf(mu.w, mu.w, sg.w * sg.w);
        lr[tid] = r;
    }

    float m2[4], s2[4];
#pragma unroll
    for (int k = 0; k < 4; ++k) {
        m2[k] = -2.f * stats[lane + 64 * k];
        s2[k] = -2.f * stats[NB + lane + 64 * k];
    }

    float acc[4][4];
#pragma unroll
    for (int k = 0; k < 4; ++k)
#pragma unroll
        for (int e = 0; e < 4; ++e) acc[k][e] = INFINITY;

    __syncthreads();

    // ---- inner loop: wave-uniform LDS broadcasts, 4 waves split the slice ----
#pragma unroll 4
    for (int iq = wid; iq < bqn; iq += 4) {
        float4 mu = lmu[iq];
        float4 sg = lsg[iq];
        float4 r  = lr [iq];
#pragma unroll
        for (int k = 0; k < 4; ++k) {
            acc[k][0] = fminf(acc[k][0], fmaf(m2[k], mu.x, fmaf(s2[k], sg.x, r.x)));
            acc[k][1] = fminf(acc[k][1], fmaf(m2[k], mu.y, fmaf(s2[k], sg.y, r.y)));
            acc[k][2] = fminf(acc[k][2], fmaf(m2[k], mu.z, fmaf(s2[k], sg.z, r.z)));
            acc[k][3] = fminf(acc[k][3], fmaf(m2[k], mu.w, fmaf(s2[k], sg.w, r.w)));
        }
    }

    // element tail (Q % 4) — block 0 / wave 0 (empty for Q=880880)
    if (blockIdx.x == 0 && wid == 0) {
        for (int q = nquad * 4; q < Q; ++q) {
            float mu = mus[q], sg = sigmas[q];
            float r = fmaf(mu, mu, sg * sg);
#pragma unroll
            for (int k = 0; k < 4; ++k)
                acc[k][0] = fminf(acc[k][0], fmaf(m2[k], mu, fmaf(s2[k], sg, r)));
        }
    }

    float a[4];
#pragma unroll
    for (int k = 0; k < 4; ++k)
        a[k] = fminf(fminf(acc[k][0], acc[k][1]), fminf(acc[k][2], acc[k][3]));

    __shared__ float red[4][NB];
#pragma unroll
    for (int k = 0; k < 4; ++k) red[wid][lane + 64 * k] = a[k];
    __syncthreads();

    float v = fminf(fminf(red[0][tid], red[1][tid]), fminf(red[2][tid], red[3][tid]));
    // un-shift: d2 = d' + (mean_b^2 + std_b^2); clamp >=0
    const float mb = stats[tid], sb = stats[NB + tid];
    v = fmaxf(v + fmaf(mb, mb, sb * sb), 0.f);

    if (ATOMIC_PATH) {
        atomicMin(&minbits[tid], __float_as_uint(v));   // nonneg: uint order == float order
    } else {
        partial[(size_t)blockIdx.x * NB + tid] = v;     // private slot, no contention
    }
}

// ---------------------------------------------------------------------------
// Kernel 3a: one block per sample; min over partials + fused final transform.
// ---------------------------------------------------------------------------
__global__ __launch_bounds__(256) void reduce_kernel(const float* __restrict__ partial,
                                                     float* __restrict__ out,
                                                     int nblocks) {
    const int b   = blockIdx.x;
    const int tid = threadIdx.x;
    float v = INFINITY;
    for (int i = tid; i < nblocks; i += 256)
        v = fminf(v, partial[(size_t)i * NB + b]);
#pragma unroll
    for (int off = 32; off > 0; off >>= 1)
        v = fminf(v, __shfl_down(v, off, 64));
    __shared__ float w[4];
    const int lane = tid & 63, wid = tid >> 6;
    if (lane == 0) w[wid] = v;
    __syncthreads();
    if (tid == 0) {
        float m = fminf(fminf(w[0], w[1]), fminf(w[2], w[3]));
        out[b] = expf(-T_K * sqrtf(m));
    }
}

// ---------------------------------------------------------------------------
// Kernel 3b (atomic fallback): T = exp(-T_k * sqrt(min_sq))
// ---------------------------------------------------------------------------
__global__ void final_kernel(const unsigned int* __restrict__ minbits,
                             float* __restrict__ out) {
    const int b = threadIdx.x;
    float d2 = __uint_as_float(minbits[b]);
    out[b] = expf(-T_K * sqrtf(d2));
}

extern "C" void kernel_launch(void* const* d_in, const int* in_sizes, int n_in,
                              void* d_out, int out_size, void* d_ws, size_t ws_size,
                              hipStream_t stream) {
    const float* features = (const float*)d_in[0];
    // d_in[1]=labels, d_in[2]=pred, d_in[3]=confidence -- unused by reference
    const float* queue_mus    = (const float*)d_in[4];
    const float* queue_sigmas = (const float*)d_in[5];
    const int Q = in_sizes[4];

    const int nquad   = Q >> 2;
    const int nblocks = (nquad + CHUNK_QUADS - 1) / CHUNK_QUADS;   // 1721 for Q=880880

    float*        stats   = (float*)d_ws;                            // 2*NB floats
    unsigned int* minbits = (unsigned int*)((float*)d_ws + 2 * NB);  // NB uints
    float*        partial = (float*)(minbits + NB);                  // nblocks*NB floats

    const size_t need = (size_t)(2 * NB) * 4 + (size_t)NB * 4 + (size_t)nblocks * NB * 4;

    stats_kernel<<<NB, 256, 0, stream>>>(features, stats, minbits);
    if (ws_size >= need) {
        scan_kernel_t<false><<<nblocks, 256, 0, stream>>>(queue_mus, queue_sigmas, stats,
                                                          partial, minbits, Q);
        reduce_kernel<<<NB, 256, 0, stream>>>(partial, (float*)d_out, nblocks);
    } else {
        scan_kernel_t<true><<<nblocks, 256, 0, stream>>>(queue_mus, queue_sigmas, stats,
                                                         partial, minbits, Q);
        final_kernel<<<1, NB, 0, stream>>>(minbits, (float*)d_out);
    }
}

// Round 13
// 17.398 us; speedup vs baseline: 8.2379x; 1.6970x over previous
//
#include <hip/hip_runtime.h>
#include <math.h>

#define NB 256
#define ND 2048
#define T_K 10.0f
#define SCAN2_BLOCKS 512
#define LDSCAP 2048            // compacted-point capacity (float2 = 16 KB LDS)

// ---------------------------------------------------------------------------
// K1: per-row mean & std (ddof=1)  +  probe pass for pruning bound.
// Probe: lane-parallel min of d^2(c0, q) over this block's queue chunk,
// c0 = (0,1) fixed. Lane-parallel costs ~12 wave-ops per 64 points (64x
// cheaper per point than the broadcast scan) -> HBM-stream bound.
// ---------------------------------------------------------------------------
__global__ __launch_bounds__(256) void stats_probe_kernel(const float* __restrict__ feat,
                                                          const float* __restrict__ mus,
                                                          const float* __restrict__ sigmas,
                                                          float* __restrict__ stats,
                                                          float* __restrict__ u0part,
                                                          int Q) {
    const int b    = blockIdx.x;
    const int tid  = threadIdx.x;
    const int lane = tid & 63, wid = tid >> 6;
    __shared__ float ls[4], lq[4];

    // ---- stats for feature row b ----
    const float4* row = (const float4*)(feat + (size_t)b * ND);
    float sum = 0.f, sumsq = 0.f;
#pragma unroll
    for (int i = 0; i < 2; ++i) {
        float4 v = row[tid + i * 256];
        sum   += v.x + v.y + v.z + v.w;
        sumsq += v.x * v.x + v.y * v.y + v.z * v.z + v.w * v.w;
    }
#pragma unroll
    for (int off = 32; off > 0; off >>= 1) {
        sum   += __shfl_down(sum, off, 64);
        sumsq += __shfl_down(sumsq, off, 64);
    }
    if (lane == 0) { ls[wid] = sum; lq[wid] = sumsq; }
    __syncthreads();
    if (tid == 0) {
        float S  = ls[0] + ls[1] + ls[2] + ls[3];
        float Q2 = lq[0] + lq[1] + lq[2] + lq[3];
        float mean = S / (float)ND;
        float var  = (Q2 - S * mean) / (float)(ND - 1);
        var = fmaxf(var, 0.f);
        stats[b]      = mean;
        stats[NB + b] = sqrtf(var);
    }

    // ---- probe: min d^2((0,1), q) over chunk [qs, qe) of quads ----
    const int nquad = Q >> 2;
    const int chunk = (nquad + NB - 1) / NB;
    const int qs    = b * chunk;
    const int qe    = min(qs + chunk, nquad);
    const float4* mu4 = (const float4*)mus;
    const float4* sg4 = (const float4*)sigmas;

    float best = INFINITY;
    for (int i = qs + tid; i < qe; i += 256) {
        float4 mu = mu4[i], sg = sg4[i];
        float s0 = sg.x - 1.f, s1 = sg.y - 1.f, s2e = sg.z - 1.f, s3 = sg.w - 1.f;
        best = fminf(best, fmaf(mu.x, mu.x, s0 * s0));
        best = fminf(best, fmaf(mu.y, mu.y, s1 * s1));
        best = fminf(best, fmaf(mu.z, mu.z, s2e * s2e));
        best = fminf(best, fmaf(mu.w, mu.w, s3 * s3));
    }
    if (b == 0) {                       // element tail (Q % 4)
        int q = nquad * 4 + tid;
        if (q < Q) {
            float dm = mus[q], ds = sigmas[q] - 1.f;
            best = fminf(best, fmaf(dm, dm, ds * ds));
        }
    }
#pragma unroll
    for (int off = 32; off > 0; off >>= 1)
        best = fminf(best, __shfl_down(best, off, 64));
    __syncthreads();                    // ls[] reuse
    if (lane == 0) ls[wid] = best;
    __syncthreads();
    if (tid == 0)
        u0part[b] = fminf(fminf(ls[0], ls[1]), fminf(ls[2], ls[3]));
}

// ---------------------------------------------------------------------------
// K2: filtered scan. Exact pruning bound:
//   q can be argmin for some sample b only if d(c0,q) <= U0 + 2R'
//   (U0 = min_q d(c0,q),  R' = max_b d(c0,b);  proof: triangle ineq.)
// Stream queue lane-parallel, LDS-compact kept points (expected ~3%),
// broadcast-scan ONLY the kept set (same math as R11/R12 scan ->
// identical results for kept points; pruned points provably irrelevant,
// threshold inflated 1e-4 to cover fp32 rounding).
// ---------------------------------------------------------------------------
__global__ __launch_bounds__(256) void scan_filtered_kernel(const float* __restrict__ mus,
                                                            const float* __restrict__ sigmas,
                                                            const float* __restrict__ stats,
                                                            const float* __restrict__ u0part,
                                                            float* __restrict__ partial,   // [SCAN2_BLOCKS*NB]
                                                            int Q) {
    const int tid  = threadIdx.x;
    const int lane = tid & 63, wid = tid >> 6;

    __shared__ float2 buf[LDSCAP];
    __shared__ float  red[4][NB];
    __shared__ float  ls[4], lq[4];
    __shared__ int    cnt;

    // ---- threshold: U0 (min over 256 probe partials), R'^2 (max over samples) ----
    float u = u0part[tid];
    float mb = stats[tid], sb = stats[NB + tid];
    float dsb = sb - 1.f;
    float r2 = fmaf(mb, mb, dsb * dsb);
#pragma unroll
    for (int off = 32; off > 0; off >>= 1) {
        u  = fminf(u,  __shfl_down(u,  off, 64));
        r2 = fmaxf(r2, __shfl_down(r2, off, 64));
    }
    if (lane == 0) { ls[wid] = u; lq[wid] = r2; }
    if (tid == 0) cnt = 0;
    __syncthreads();
    const float U0  = fminf(fminf(ls[0], ls[1]), fminf(ls[2], ls[3]));
    const float R2  = fmaxf(fmaxf(lq[0], lq[1]), fmaxf(lq[2], lq[3]));
    const float thr = sqrtf(U0) + 2.f * sqrtf(R2);
    const float thr2 = thr * thr * 1.0001f + 1e-12f;   // inflated: covers fp32 rounding

    // per-lane sample constants (samples b = lane + 64k)
    float m2[4], s2[4];
#pragma unroll
    for (int k = 0; k < 4; ++k) {
        m2[k] = -2.f * stats[lane + 64 * k];
        s2[k] = -2.f * stats[NB + lane + 64 * k];
    }
    float acc[4];
#pragma unroll
    for (int k = 0; k < 4; ++k) acc[k] = INFINITY;

    const int nquad = Q >> 2;
    const float4* mu4 = (const float4*)mus;
    const float4* sg4 = (const float4*)sigmas;

    // block-uniform chunked grid-stride (barriers inside must be uniform)
    for (int cb = blockIdx.x * 256; cb < nquad; cb += SCAN2_BLOCKS * 256) {
        __syncthreads();                              // appends settled, cnt uniform
        if (cnt > LDSCAP - 1024) {                    // room for worst-case 1024 appends
            const int n = cnt;
            for (int j = wid; j < n; j += 4) {
                float2 p = buf[j];
                float r = fmaf(p.x, p.x, p.y * p.y);
#pragma unroll
                for (int k = 0; k < 4; ++k)
                    acc[k] = fminf(acc[k], fmaf(m2[k], p.x, fmaf(s2[k], p.y, r)));
            }
            __syncthreads();
            if (tid == 0) cnt = 0;
            __syncthreads();
        }
        const int i = cb + tid;
        if (i < nquad) {
            float4 mu = mu4[i], sg = sg4[i];
#define TESTK(MX, SX)                                                        \
            {                                                                \
                float dm = (MX), dss = (SX) - 1.f;                           \
                float dd = fmaf(dm, dm, dss * dss);                          \
                if (dd <= thr2) {                                            \
                    int p = atomicAdd(&cnt, 1);                              \
                    buf[p] = make_float2((MX), (SX));                        \
                }                                                            \
            }
            TESTK(mu.x, sg.x)
            TESTK(mu.y, sg.y)
            TESTK(mu.z, sg.z)
            TESTK(mu.w, sg.w)
        }
    }
    // element tail (Q % 4) — block 0 (empty for Q=880880)
    if (blockIdx.x == 0) {
        int q = nquad * 4 + tid;
        if (q < Q) { TESTK(mus[q], sigmas[q]) }
    }
#undef TESTK

    // final flush
    __syncthreads();
    {
        const int n = cnt;
        for (int j = wid; j < n; j += 4) {
            float2 p = buf[j];
            float r = fmaf(p.x, p.x, p.y * p.y);
#pragma unroll
            for (int k = 0; k < 4; ++k)
                acc[k] = fminf(acc[k], fmaf(m2[k], p.x, fmaf(s2[k], p.y, r)));
        }
    }

    // merge 4 waves, un-shift by c_b = m_b^2 + s_b^2, write private partial
    __syncthreads();
#pragma unroll
    for (int k = 0; k < 4; ++k) red[wid][lane + 64 * k] = acc[k];
    __syncthreads();
    float v = fminf(fminf(red[0][tid], red[1][tid]), fminf(red[2][tid], red[3][tid]));
    v = v + fmaf(mb, mb, sb * sb);
    partial[(size_t)blockIdx.x * NB + tid] = fmaxf(v, 0.f);
}

// ---------------------------------------------------------------------------
// K3: one block per sample; min over partials + fused T = exp(-k*sqrt(d2)).
// ---------------------------------------------------------------------------
__global__ __launch_bounds__(256) void reduce_kernel(const float* __restrict__ partial,
                                                     float* __restrict__ out,
                                                     int nblocks) {
    const int b   = blockIdx.x;
    const int tid = threadIdx.x;
    float v = INFINITY;
    for (int i = tid; i < nblocks; i += 256)
        v = fminf(v, partial[(size_t)i * NB + b]);
#pragma unroll
    for (int off = 32; off > 0; off >>= 1)
        v = fminf(v, __shfl_down(v, off, 64));
    __shared__ float w[4];
    const int lane = tid & 63, wid = tid >> 6;
    if (lane == 0) w[wid] = v;
    __syncthreads();
    if (tid == 0) {
        float m = fminf(fminf(w[0], w[1]), fminf(w[2], w[3]));
        out[b] = expf(-T_K * sqrtf(m));
    }
}

extern "C" void kernel_launch(void* const* d_in, const int* in_sizes, int n_in,
                              void* d_out, int out_size, void* d_ws, size_t ws_size,
                              hipStream_t stream) {
    const float* features = (const float*)d_in[0];
    // d_in[1]=labels, d_in[2]=pred, d_in[3]=confidence -- unused by reference
    const float* queue_mus    = (const float*)d_in[4];
    const float* queue_sigmas = (const float*)d_in[5];
    const int Q = in_sizes[4];

    float* stats   = (float*)d_ws;                 // 2*NB floats
    float* u0part  = stats + 2 * NB;               // NB floats
    float* partial = u0part + NB;                  // SCAN2_BLOCKS*NB floats (512 KB)

    stats_probe_kernel<<<NB, 256, 0, stream>>>(features, queue_mus, queue_sigmas,
                                               stats, u0part, Q);
    scan_filtered_kernel<<<SCAN2_BLOCKS, 256, 0, stream>>>(queue_mus, queue_sigmas,
                                                           stats, u0part, partial, Q);
    reduce_kernel<<<NB, 256, 0, stream>>>(partial, (float*)d_out, SCAN2_BLOCKS);
}